// Round 8
// baseline (343.889 us; speedup 1.0000x reference)
//
#include <hip/hip_runtime.h>
#include <math.h>

// NoisyTopkRouter: B=8,T=4096,NE=1024,E=16,TOPK=2,LIN=1824
// out = [router 32768*16][indices 32768*2][gate1 32768*16] all f32
//
// R12: REQUEST-GRAIN experiment. R4..R11 falsified latency, occupancy,
// pipeline depth, staging mechanism, and cross-block scheduling; all serve
// memory at ~2.5 TB/s (HBM ~1.05). The never-varied variable: every wave
// VMEM instruction presents 256-B row fragments (16 lanes x 16B per token
// row). m13's 6.3 TB/s copy presents 1KB/instr contiguous. 256B/activate
// -> ~20% DRAM efficiency = the invariant. Fix: BK=128 -> each DMA instr
// covers 2 x 512-B contiguous segments (2x the burst per activate).
// Held fixed (proven machinery): TOKS=128, 512 thr/8 waves, lane=8tok x 8e,
// wave k-slab 16 (4 q-phases), fmac:b128=16, rule-#21 swizzle (now XOR
// within 16-f4 halves of the 32-f4 row), W reg-staged single buffer with
// R11's publish cadence, 8-way split-K reduction + proven epilogue.
// LDS: A dbuf 2x64KB + W 16KB = 144.4KB -> 1 block/CU. 14 steps.

#define NSTEP 14
#define I_OFF 524288        // 32768*16
#define G_OFF 589824        // 524288 + 32768*2
#define SS 36               // score-row stride (reduction scratch)

__device__ __forceinline__ float softplus_f(float x) {
  return fmaxf(x, 0.0f) + log1pf(expf(-fabsf(x)));
}

__device__ __forceinline__ float get_comp(const float4& v, int kk) {
  return kk == 0 ? v.x : kk == 1 ? v.y : kk == 2 ? v.z : v.w;
}

__device__ __forceinline__ void dma16(const float* g, float* l) {
  __builtin_amdgcn_global_load_lds(
      (const __attribute__((address_space(1))) void*)g,
      (__attribute__((address_space(3))) void*)l, 16, 0, 0);
}

__global__ __launch_bounds__(512, 1) void router_kernel(
    const float* __restrict__ mh, const float* __restrict__ dt,
    const float* __restrict__ dd, const float* __restrict__ rg,
    const float* __restrict__ de, const float* __restrict__ cemb_all,
    const float* __restrict__ w_route, const float* __restrict__ b_route,
    const float* __restrict__ w_noise, const float* __restrict__ b_noise,
    const float* __restrict__ eps, const int* __restrict__ city_index,
    float* __restrict__ out) {
  // A0 [128][32 f4] @0 (16384 f) | A1 @16384 | sW [128][32] @32768 (4096 f)
  // post-loop overlay in dead A0: sS [128][36] @0 (4608 f), city @4608
  __shared__ float smem[36864];   // 147456 B -> 1 block/CU
  float* sA0 = smem;
  float* sA1 = smem + 16384;
  float* sW  = smem + 32768;
  float* sS  = smem;
  float* cityL = smem + 4608;

  const int tid = threadIdx.x;
  const int w   = tid >> 6;        // wave 0..7: k-rows [w*16, w*16+16) of step
  const int ln  = tid & 63;
  const int tg  = ln & 15;         // tokens {tg + 16j}, j=0..7
  const int eg  = ln >> 4;         // e-cols eg*8..eg*8+7 (of 32 = route|noise)
  const int blockTok = blockIdx.x * 128;

  float4 accL[8], accH[8];
#pragma unroll
  for (int j = 0; j < 8; ++j) {
    accL[j] = make_float4(0.f, 0.f, 0.f, 0.f);
    accH[j] = make_float4(0.f, 0.f, 0.f, 0.f);
  }

  // row-start of step s's 128-float window for global token row (blockTok+r)
  auto a_src = [&](int s, int r) -> const float* {
    const size_t gr = blockTok + r;
    if (s < 8)  return mh + gr * 1024 + s * 128;
    if (s < 10) return dt + gr * 256 + (s - 8) * 128;
    if (s < 12) return dd + gr * 256 + (s - 10) * 128;
    if (s == 12) return rg + gr * 128;
    return de + gr * 128;
  };

  // A: 4096 f4 slots, 8 DMA/thread. Wave instr = 64 consecutive slots =
  // 2 rows x 512B contiguous (the grain fix). LDS dest linear; source col
  // XOR-swizzled within each 16-f4 half: c4 = (p&16) | ((p&15)^(r&15)).
  auto stageA = [&](int s, float* Ab) {
#pragma unroll
    for (int i = 0; i < 8; ++i) {
      const int slot = i * 512 + tid;
      const int r    = slot >> 5;                 // token row 0..127
      const int p    = slot & 31;                 // physical f4-col
      const int c4   = (p & 16) | ((p & 15) ^ (r & 15));
      dma16(a_src(s, r) + c4 * 4, Ab + slot * 4);
    }
  };

  // W step = 128 k-rows x 32 e = 1024 f4; 2 f4/thread into regs.
  auto wglb = [&](int s, float4& w0, float4& w1) {
#pragma unroll
    for (int i = 0; i < 2; ++i) {
      const int slot = i * 512 + tid;
      const int kr   = slot >> 3;            // k-row 0..127
      const int c4   = slot & 7;             // 8 f4 per row (32 e)
      const int wrow = s * 128 + ((s >= 8) ? 32 : 0) + kr;  // skip city rows
      const float* p = (c4 < 4) ? (w_route + wrow * 16 + c4 * 4)
                                : (w_noise + wrow * 16 + (c4 - 4) * 4);
      if (i == 0) w0 = *(const float4*)p; else w1 = *(const float4*)p;
    }
  };

  float4 WR0, WR1;
  stageA(0, sA0);
  wglb(0, WR0, WR1);
  asm volatile("s_waitcnt vmcnt(0)" ::: "memory");
  __syncthreads();
  *(float4*)&sW[tid * 4]         = WR0;
  *(float4*)&sW[(tid + 512) * 4] = WR1;
  __syncthreads();

  for (int s = 0; s < NSTEP; ++s) {
    const float* A = (s & 1) ? sA1 : sA0;

    if (s + 1 < NSTEP) {               // into buffer freed at end of s-1
      stageA(s + 1, (s & 1) ? sA0 : sA1);
      wglb(s + 1, WR0, WR1);
    }

#pragma unroll
    for (int q = 0; q < 4; ++q) {
      const int L  = w * 4 + q;                        // logical f4-col 0..31
      const int p4 = ((L & 16) | ((L & 15) ^ tg)) * 4; // swizzled, j-indep
      float4 a[8];
#pragma unroll
      for (int j = 0; j < 8; ++j)
        a[j] = *(const float4*)&A[(tg + 16 * j) * 128 + p4];
#pragma unroll
      for (int kk = 0; kk < 4; ++kk) {
        const int krow = L * 4 + kk;                   // = w*16 + q*4 + kk
        float4 wv0 = *(const float4*)&sW[krow * 32 + eg * 8];      // bcast
        float4 wv1 = *(const float4*)&sW[krow * 32 + eg * 8 + 4];  // bcast
#pragma unroll
        for (int j = 0; j < 8; ++j) {
          const float sv = get_comp(a[j], kk);
          accL[j].x = fmaf(sv, wv0.x, accL[j].x);
          accL[j].y = fmaf(sv, wv0.y, accL[j].y);
          accL[j].z = fmaf(sv, wv0.z, accL[j].z);
          accL[j].w = fmaf(sv, wv0.w, accL[j].w);
          accH[j].x = fmaf(sv, wv1.x, accH[j].x);
          accH[j].y = fmaf(sv, wv1.y, accH[j].y);
          accH[j].z = fmaf(sv, wv1.z, accH[j].z);
          accH[j].w = fmaf(sv, wv1.w, accH[j].w);
        }
      }
    }

    asm volatile("s_waitcnt vmcnt(0)" ::: "memory");  // A(s+1)/W(s+1) landed
    __syncthreads();                 // everyone done with A(s) and sW(s)
    if (s + 1 < NSTEP) {
      *(float4*)&sW[tid * 4]         = WR0;   // publish W(s+1)
      *(float4*)&sW[(tid + 512) * 4] = WR1;
      __syncthreads();
    }
  }

  // ---- city constants into dead A0 region (consumed by epilogue) ----
  if (tid < 32) {
    const int e = tid & 15;
    const float* wsrc = (tid < 16) ? w_route : w_noise;
    const float* bsrc = (tid < 16) ? b_route : b_noise;
    const float* ce = cemb_all + city_index[0] * 32;
    float sacc = bsrc[e];
#pragma unroll
    for (int j = 0; j < 32; ++j)
      sacc = fmaf(ce[j], wsrc[(1024 + j) * 16 + e], sacc);
    cityL[tid] = sacc;
  }

  // ---- 8-way split-K reduction: serial RMW rounds into sS[128][36] ----
  // (sS overlays A0; last step s=13 computed from A1: safe)
  for (int r = 0; r < 8; ++r) {
    if (w == r) {
#pragma unroll
      for (int j = 0; j < 8; ++j) {
        float* p = &sS[(tg + 16 * j) * SS + eg * 8];
        if (r == 0) {
          *(float4*)(p)     = accL[j];
          *(float4*)(p + 4) = accH[j];
        } else {
          float4 x0 = *(float4*)(p), x1 = *(float4*)(p + 4);
          x0.x += accL[j].x; x0.y += accL[j].y; x0.z += accL[j].z; x0.w += accL[j].w;
          x1.x += accH[j].x; x1.y += accH[j].y; x1.z += accH[j].z; x1.w += accH[j].w;
          *(float4*)(p)     = x0;
          *(float4*)(p + 4) = x1;
        }
      }
    }
    __syncthreads();
  }

  // ---- epilogue: one lane per token ----
  if (tid < 128) {
    const int tokg = blockTok + tid;
    float l[32];
#pragma unroll
    for (int e4 = 0; e4 < 8; ++e4) {
      float4 s0 = *(const float4*)&sS[tid * SS + e4 * 4];
      l[e4 * 4 + 0] = s0.x; l[e4 * 4 + 1] = s0.y;
      l[e4 * 4 + 2] = s0.z; l[e4 * 4 + 3] = s0.w;
    }
#pragma unroll
    for (int e = 0; e < 32; ++e) l[e] += cityL[e];

    const float* ep = eps + (size_t)tokg * 16;
    float n[16];
#pragma unroll
    for (int e = 0; e < 16; ++e)
      n[e] = fmaf(ep[e], softplus_f(l[16 + e]), l[e]);

    // top-2, lowest-index tie-break (matches lax.top_k)
    float m1 = -INFINITY; int i1 = 0;
#pragma unroll
    for (int e = 0; e < 16; ++e)
      if (n[e] > m1) { m1 = n[e]; i1 = e; }
    float m2 = -INFINITY; int i2 = 0;
#pragma unroll
    for (int e = 0; e < 16; ++e)
      if (e != i1 && n[e] > m2) { m2 = n[e]; i2 = e; }

    float ex[16], Z = 0.f;
#pragma unroll
    for (int e = 0; e < 16; ++e) { ex[e] = expf(n[e] - m1); Z += ex[e]; }
    const float invZ  = 1.0f / Z;
    const float invZ2 = 1.0f / (1.0f + expf(m2 - m1));  // ex[i1]=1

    float r[16], g1[16];
#pragma unroll
    for (int e = 0; e < 16; ++e) {
      r[e]  = (e == i1 || e == i2) ? ex[e] * invZ2 : 0.0f;
      g1[e] = ex[e] * invZ;
    }

    float* ro = out + (size_t)tokg * 16;
#pragma unroll
    for (int e4 = 0; e4 < 4; ++e4)
      *(float4*)(ro + e4 * 4) = make_float4(r[e4*4], r[e4*4+1], r[e4*4+2], r[e4*4+3]);

    out[I_OFF + (size_t)tokg * 2 + 0] = (float)i1;
    out[I_OFF + (size_t)tokg * 2 + 1] = (float)i2;

    float* go = out + G_OFF + (size_t)tokg * 16;
#pragma unroll
    for (int e4 = 0; e4 < 4; ++e4)
      *(float4*)(go + e4 * 4) = make_float4(g1[e4*4], g1[e4*4+1], g1[e4*4+2], g1[e4*4+3]);
  }
}

extern "C" void kernel_launch(void* const* d_in, const int* in_sizes, int n_in,
                              void* d_out, int out_size, void* d_ws, size_t ws_size,
                              hipStream_t stream) {
  const float* mh = (const float*)d_in[0];   // [8,4096,1024]
  const float* dt = (const float*)d_in[1];   // [8,4096,256]
  const float* dd = (const float*)d_in[2];   // [8,4096,256]
  const float* rg = (const float*)d_in[3];   // [8,4096,128]
  const float* de = (const float*)d_in[4];   // [8,4096,128]
  const float* ce = (const float*)d_in[5];   // [4,32]
  const float* wr = (const float*)d_in[6];   // [1824,16]
  const float* br = (const float*)d_in[7];   // [16]
  const float* wn = (const float*)d_in[8];   // [1824,16]
  const float* bn = (const float*)d_in[9];   // [16]
  const float* ep = (const float*)d_in[10];  // [8,4096,16]
  const int*   ci = (const int*)d_in[11];    // scalar
  float* out = (float*)d_out;

  router_kernel<<<256, 512, 0, stream>>>(mh, dt, dd, rg, de, ce, wr, br, wn, bn,
                                         ep, ci, out);
}

// Round 9
// 296.352 us; speedup vs baseline: 1.1604x; 1.1604x over previous
//
#include <hip/hip_runtime.h>
#include <math.h>

// NoisyTopkRouter: B=8,T=4096,NE=1024,E=16,TOPK=2,LIN=1824
// out = [router 32768*16][indices 32768*2][gate1 32768*16] all f32
//
// R13: serial-tail shaving on the R9 champion (115us). Ledger: R4/R9/R10/
// R11/R12 all serve L2-miss traffic at ~2.45 TB/s invariant -> floor =
// 237MB/2.45 = ~97us; the 18% gap is serial tails, not streaming rate.
// Changes vs R9 (structure otherwise identical):
//  (1) tree reduction: 3 barriers (write4/add4, write2/add2, write1/add1)
//      instead of 8 serial-RMW rounds; wave 0 ends holding final sums and
//      runs the epilogue with no further barriers. SP=36 (16B-aligned,
//      2-way banks = free).
//  (2) city-const computation moved into the PROLOGUE, overlapped with the
//      chunk-0 DMA wait (was a post-loop serial block).
//  (3) eps prefetched into regs right after the main loop; its latency
//      hides under the reduction barriers.
// Proven machinery kept: global_load_lds DMA, linear LDS dest + XOR-
// swizzled global source + same-XOR read (rule #21), vmcnt(0)+barrier per
// chunk, TOKS=64/512thr/8 waves/2 blocks/CU, lane tile 4tok x 8e.

#define TOKS 64
#define NCHUNK 28
#define I_OFF 524288        // 32768*16
#define G_OFF 589824        // 524288 + 32768*2
#define SP 36               // slab row stride: 16B-aligned, 2-way banks

__device__ __forceinline__ float softplus_f(float x) {
  // jax.nn.softplus = max(x,0) + log1p(exp(-|x|))
  return fmaxf(x, 0.0f) + log1pf(expf(-fabsf(x)));
}

__device__ __forceinline__ float get_comp(const float4& v, int kk) {
  return kk == 0 ? v.x : kk == 1 ? v.y : kk == 2 ? v.z : v.w;
}

__device__ __forceinline__ void dma16(const float* g, float* l) {
  __builtin_amdgcn_global_load_lds(
      (const __attribute__((address_space(1))) void*)g,
      (__attribute__((address_space(3))) void*)l, 16, 0, 0);
}

__global__ __launch_bounds__(512, 2) void router_kernel(
    const float* __restrict__ mh, const float* __restrict__ dt,
    const float* __restrict__ dd, const float* __restrict__ rg,
    const float* __restrict__ de, const float* __restrict__ cemb_all,
    const float* __restrict__ w_route, const float* __restrict__ b_route,
    const float* __restrict__ w_noise, const float* __restrict__ b_noise,
    const float* __restrict__ eps, const int* __restrict__ city_index,
    float* __restrict__ out) {
  // [0,4096) A0 | [4096,8192) A1 | [8192,10240) W0 | [10240,12288) W1
  // post-loop overlay: 4 slabs [64][36] = 2304 f each at slot*2304
  __shared__ float smem[12288];   // 49152 B -> 2 blocks/CU
  __shared__ float city_s[32];
  float* sA0 = smem;
  float* sA1 = smem + 4096;
  float* sW0 = smem + 8192;
  float* sW1 = smem + 10240;

  const int tid = threadIdx.x;
  const int w   = tid >> 6;        // wave 0..7: k-slab [w*8, w*8+8) of chunk
  const int ln  = tid & 63;
  const int tg  = ln & 15;         // tokens {tg + 16j}, j=0..3
  const int eg  = ln >> 4;         // e-cols eg*8..eg*8+7 (of 32 = route|noise)
  const int blockTok = blockIdx.x * TOKS;

  float4 accL[4], accH[4];
#pragma unroll
  for (int j = 0; j < 4; ++j) {
    accL[j] = make_float4(0.f, 0.f, 0.f, 0.f);
    accH[j] = make_float4(0.f, 0.f, 0.f, 0.f);
  }

  auto a_src = [&](int g, int row) -> const float* {
    const float* base; int stride;
    if (g < 16)      { base = mh + g * 64;        stride = 1024; }
    else if (g < 20) { base = dt + (g - 16) * 64; stride = 256; }
    else if (g < 24) { base = dd + (g - 20) * 64; stride = 256; }
    else             { base = (g < 26) ? rg + (g - 24) * 64
                                       : de + (g - 26) * 64;
                       stride = 128; }
    return base + (size_t)(blockTok + row) * stride;
  };

  // DMA one chunk: A 1024 f4 slots (2/thread), W 512 f4 (1/thread).
  // LDS dest LINEAR slot*16B; A source col pre-swizzled: LDS slot (r,p)
  // holds global f4-col p^(r&15) (inside the row's 256B segment).
  auto stageDMA = [&](int g, float* Abuf, float* Wbuf) {
#pragma unroll
    for (int i = 0; i < 2; ++i) {
      const int slot = i * 512 + tid;
      const int r    = slot >> 4;                 // token row 0..63
      const int c4   = (slot & 15) ^ (r & 15);    // swizzled source col
      dma16(a_src(g, r) + c4 * 4, Abuf + slot * 4);
    }
    {
      const int r  = tid >> 3;               // k-row 0..63
      const int c4 = tid & 7;                // 8 f4 per row (32 e)
      const int kb = g * 64 + ((g >= 16) ? 32 : 0) + r;  // skip city rows
      const float* ws = (c4 < 4) ? (w_route + kb * 16 + c4 * 4)
                                 : (w_noise + kb * 16 + (c4 - 4) * 4);
      dma16(ws, Wbuf + tid * 4);
    }
  };

  stageDMA(0, sA0, sW0);

  // ---- city constants: overlapped with chunk-0 DMA flight ----
  if (tid < 32) {
    const int e = tid & 15;
    const float* wsrc = (tid < 16) ? w_route : w_noise;
    const float* bsrc = (tid < 16) ? b_route : b_noise;
    const float* ce = cemb_all + city_index[0] * 32;
    float sacc = bsrc[e];
#pragma unroll
    for (int j = 0; j < 32; ++j)
      sacc = fmaf(ce[j], wsrc[(1024 + j) * 16 + e], sacc);
    city_s[tid] = sacc;
  }

  asm volatile("s_waitcnt vmcnt(0)" ::: "memory");
  __syncthreads();   // chunk 0 resident, city_s published

  // lane-fixed read addressing (swizzled A columns, j-independent)
  const int c4x0 = (((w << 1) | 0) ^ tg) << 2;   // float offset of f4 slot
  const int c4x1 = (((w << 1) | 1) ^ tg) << 2;
  const int k0 = w * 8;

  for (int c = 0; c < NCHUNK; ++c) {
    const float* A = (c & 1) ? sA1 : sA0;
    const float* W = (c & 1) ? sW1 : sW0;

    if (c + 1 < NCHUNK)
      stageDMA(c + 1, (c & 1) ? sA0 : sA1, (c & 1) ? sW0 : sW1);

#pragma unroll
    for (int q = 0; q < 2; ++q) {
      const int cofs = q ? c4x1 : c4x0;
      float4 a[4];
#pragma unroll
      for (int j = 0; j < 4; ++j)
        a[j] = *(const float4*)&A[(tg + 16 * j) * 64 + cofs];  // 2-way: free
#pragma unroll
      for (int kk = 0; kk < 4; ++kk) {
        const int krow = k0 + q * 4 + kk;
        float4 wv0 = *(const float4*)&W[krow * 32 + eg * 8];      // bcast
        float4 wv1 = *(const float4*)&W[krow * 32 + eg * 8 + 4];  // bcast
#pragma unroll
        for (int j = 0; j < 4; ++j) {
          const float s = get_comp(a[j], kk);
          accL[j].x = fmaf(s, wv0.x, accL[j].x);
          accL[j].y = fmaf(s, wv0.y, accL[j].y);
          accL[j].z = fmaf(s, wv0.z, accL[j].z);
          accL[j].w = fmaf(s, wv0.w, accL[j].w);
          accH[j].x = fmaf(s, wv1.x, accH[j].x);
          accH[j].y = fmaf(s, wv1.y, accH[j].y);
          accH[j].z = fmaf(s, wv1.z, accH[j].z);
          accH[j].w = fmaf(s, wv1.w, accH[j].w);
        }
      }
    }

    asm volatile("s_waitcnt vmcnt(0)" ::: "memory");  // next chunk's DMA done
    __syncthreads();   // all reads of current buffer done
  }
  // entire smem (A/W buffers) is dead now; accs live in regs.

  // ---- eps prefetch: hide under the reduction barriers ----
  float4 ep0, ep1, ep2, ep3;
  if (tid < TOKS) {
    const float* ep = eps + (size_t)(blockTok + tid) * 16;
    ep0 = *(const float4*)(ep +  0);
    ep1 = *(const float4*)(ep +  4);
    ep2 = *(const float4*)(ep +  8);
    ep3 = *(const float4*)(ep + 12);
  }

  // ---- tree reduction: 8 wave-partials -> wave 0, 3 barriers ----
  // slab[slot] = smem + slot*2304, [64][SP]; lane writes 4 rows x 2 f4.
  auto writeP = [&](int slot) {
    float* Sb = smem + slot * 2304;
#pragma unroll
    for (int j = 0; j < 4; ++j) {
      float* p = &Sb[(tg + 16 * j) * SP + eg * 8];
      *(float4*)(p)     = accL[j];
      *(float4*)(p + 4) = accH[j];
    }
  };
  auto addP = [&](int slot) {
    const float* Sb = smem + slot * 2304;
#pragma unroll
    for (int j = 0; j < 4; ++j) {
      const float* p = &Sb[(tg + 16 * j) * SP + eg * 8];
      float4 x0 = *(const float4*)(p), x1 = *(const float4*)(p + 4);
      accL[j].x += x0.x; accL[j].y += x0.y; accL[j].z += x0.z; accL[j].w += x0.w;
      accH[j].x += x1.x; accH[j].y += x1.y; accH[j].z += x1.z; accH[j].w += x1.w;
    }
  };

  if (w >= 4) writeP(w - 4);          // waves 4..7 -> slots 0..3
  __syncthreads();
  if (w < 4) addP(w);
  __syncthreads();                    // (waves 4..7 idle from here)
  if (w == 2 || w == 3) writeP(w - 2);
  __syncthreads();
  if (w < 2) addP(w);
  __syncthreads();
  if (w == 1) writeP(0);
  __syncthreads();
  if (w == 0) {
    addP(0);
    writeP(0);                        // slot 0 <- final sums (wave-0 private)
  }

  // ---- epilogue: wave 0 only (tid 0..63 = one lane per token) ----
  if (tid < TOKS) {
    const int tokg = blockTok + tid;
    const float* Sb = smem + tid * SP;   // slot 0, row tid
    float l[32];
#pragma unroll
    for (int e4 = 0; e4 < 8; ++e4) {
      float4 s0 = *(const float4*)&Sb[e4 * 4];
      l[e4 * 4 + 0] = s0.x; l[e4 * 4 + 1] = s0.y;
      l[e4 * 4 + 2] = s0.z; l[e4 * 4 + 3] = s0.w;
    }
#pragma unroll
    for (int e = 0; e < 32; ++e) l[e] += city_s[e];

    float n[16];
    {
      const float epv[16] = {ep0.x, ep0.y, ep0.z, ep0.w,
                             ep1.x, ep1.y, ep1.z, ep1.w,
                             ep2.x, ep2.y, ep2.z, ep2.w,
                             ep3.x, ep3.y, ep3.z, ep3.w};
#pragma unroll
      for (int e = 0; e < 16; ++e)
        n[e] = fmaf(epv[e], softplus_f(l[16 + e]), l[e]);
    }

    // top-2, lowest-index tie-break (matches lax.top_k)
    float m1 = -INFINITY; int i1 = 0;
#pragma unroll
    for (int e = 0; e < 16; ++e)
      if (n[e] > m1) { m1 = n[e]; i1 = e; }
    float m2 = -INFINITY; int i2 = 0;
#pragma unroll
    for (int e = 0; e < 16; ++e)
      if (e != i1 && n[e] > m2) { m2 = n[e]; i2 = e; }

    float ex[16], Z = 0.f;
#pragma unroll
    for (int e = 0; e < 16; ++e) { ex[e] = expf(n[e] - m1); Z += ex[e]; }
    const float invZ  = 1.0f / Z;
    const float invZ2 = 1.0f / (1.0f + expf(m2 - m1));  // ex[i1]=1

    float r[16], g1[16];
#pragma unroll
    for (int e = 0; e < 16; ++e) {
      r[e]  = (e == i1 || e == i2) ? ex[e] * invZ2 : 0.0f;
      g1[e] = ex[e] * invZ;
    }

    float* ro = out + (size_t)tokg * 16;
#pragma unroll
    for (int e4 = 0; e4 < 4; ++e4)
      *(float4*)(ro + e4 * 4) = make_float4(r[e4*4], r[e4*4+1], r[e4*4+2], r[e4*4+3]);

    out[I_OFF + (size_t)tokg * 2 + 0] = (float)i1;
    out[I_OFF + (size_t)tokg * 2 + 1] = (float)i2;

    float* go = out + G_OFF + (size_t)tokg * 16;
#pragma unroll
    for (int e4 = 0; e4 < 4; ++e4)
      *(float4*)(go + e4 * 4) = make_float4(g1[e4*4], g1[e4*4+1], g1[e4*4+2], g1[e4*4+3]);
  }
}

extern "C" void kernel_launch(void* const* d_in, const int* in_sizes, int n_in,
                              void* d_out, int out_size, void* d_ws, size_t ws_size,
                              hipStream_t stream) {
  const float* mh = (const float*)d_in[0];   // [8,4096,1024]
  const float* dt = (const float*)d_in[1];   // [8,4096,256]
  const float* dd = (const float*)d_in[2];   // [8,4096,256]
  const float* rg = (const float*)d_in[3];   // [8,4096,128]
  const float* de = (const float*)d_in[4];   // [8,4096,128]
  const float* ce = (const float*)d_in[5];   // [4,32]
  const float* wr = (const float*)d_in[6];   // [1824,16]
  const float* br = (const float*)d_in[7];   // [16]
  const float* wn = (const float*)d_in[8];   // [1824,16]
  const float* bn = (const float*)d_in[9];   // [16]
  const float* ep = (const float*)d_in[10];  // [8,4096,16]
  const int*   ci = (const int*)d_in[11];    // scalar
  float* out = (float*)d_out;

  router_kernel<<<512, 512, 0, stream>>>(mh, dt, dd, rg, de, ce, wr, br, wn, bn,
                                         ep, ci, out);
}